// Round 4
// baseline (29.128 us; speedup 1.0000x reference)
//
#include <hip/hip_runtime.h>
#include <math.h>

#define N_SIZE 4096
#define B_SIZE 8192
#define T 4                     // trials per wave
#define NHALF 2048              // j elements per wave (half of N)

typedef float v2f __attribute__((ext_vector_type(2)));

__device__ __forceinline__ float wave_sum(float v) {
#pragma unroll
    for (int off = 32; off >= 1; off >>= 1)
        v += __shfl_xor(v, off, 64);
    return v;
}

// Clamped Pade(5,4) from the tanh continued fraction:
// tanh x ~= x*(945 + 105u + u^2) / (945 + 420u + 15u^2), u = x^2, |x|<=4.
// Max abs err ~2.3e-3 at the clamp; all VALU except 2x v_rcp_f32.
__device__ __forceinline__ v2f tanh2(v2f x) {
    x = __builtin_elementwise_max(__builtin_elementwise_min(x, (v2f)(4.0f)), (v2f)(-4.0f));
    v2f u   = x * x;
    v2f num = (u + 105.0f) * u + 945.0f;
    v2f den = (u * 15.0f + 420.0f) * u + 945.0f;
    v2f r;
    r.x = __builtin_amdgcn_rcpf(den.x);
    r.y = __builtin_amdgcn_rcpf(den.y);
    return x * num * r;
}

__global__ __launch_bounds__(1024)
void bif_kernel(const float* __restrict__ k_t,
                const float* __restrict__ phase,
                const float* __restrict__ mono,
                const float* __restrict__ dKn,
                const float* __restrict__ amp_p,
                const float* __restrict__ w_p,
                const float* __restrict__ stim,
                const float* __restrict__ alpha,
                const float* __restrict__ Im,
                const float* __restrict__ mm,
                const float* __restrict__ nm,
                float* __restrict__ out) {
    __shared__ float s_m0[N_SIZE], s_m1[N_SIZE], s_n0[N_SIZE], s_n1[N_SIZE];
    __shared__ float s_I0[N_SIZE], s_cv[N_SIZE];
    __shared__ float s_red[8 * 2 * 6 * T];   // [group][half][acc][trial]

    const int tid  = threadIdx.x;
    const int lane = tid & 63;
    const int wvi  = tid >> 6;      // 0..15
    const int g    = wvi >> 1;      // 0..7 trial group
    const int h    = wvi & 1;       // j-half
    const int b0   = blockIdx.x * 32 + g * T;

    const float st0 = stim[0];
    const float st1 = stim[1];

    // ---- stage all 96KB once: 1024 threads x 4 floats per array ----
    {
        const int t4 = tid * 4;
        *(float4*)&s_m0[t4] = *(const float4*)&mm[t4];
        *(float4*)&s_m1[t4] = *(const float4*)&mm[N_SIZE + t4];
        *(float4*)&s_n0[t4] = *(const float4*)&nm[t4];
        *(float4*)&s_n1[t4] = *(const float4*)&nm[N_SIZE + t4];
        *(float4*)&s_I0[t4] = *(const float4*)&Im[t4];
        float4 i1 = *(const float4*)&Im[N_SIZE + t4];
        float4 i2 = *(const float4*)&Im[2 * N_SIZE + t4];
        float4 cv;
        cv.x = st0 * i1.x + st1 * i2.x;
        cv.y = st0 * i1.y + st1 * i2.y;
        cv.z = st0 * i1.z + st1 * i2.z;
        cv.w = st0 * i1.w + st1 * i2.w;
        *(float4*)&s_cv[t4] = cv;
    }

    // ---- per-trial params (uniform across lanes) ----
    const float amp = amp_p[0];
    const float w   = w_p[0];
    const float tau_sw = w * 0.1f;
    const float phi0 = atanf(tau_sw);
    const float vamp = amp / sqrtf(1.0f + tau_sw * tau_sw);

    float k0[T], k1[T], vo[T];
#pragma unroll
    for (int t = 0; t < T; ++t) {
        const int b = b0 + t;
        k0[t] = k_t[2 * b];
        k1[t] = k_t[2 * b + 1];
        vo[t] = vamp * sinf(phase[b] - phi0);
    }

    // ---- hoist epilogue globals into registers (hide latency under loop) ----
    float  e_k0 = 0.f, e_k1 = 0.f, e_p = 0.f, e_dn = 0.f;
    float4 e_mono = {0.f, 0.f, 0.f, 0.f};
    if (h == 0 && lane < T) {
        const int b = b0 + lane;
        e_k0 = k_t[2 * b];
        e_k1 = k_t[2 * b + 1];
        e_p  = phase[b];
        e_dn = dKn[b];
        e_mono = *(const float4*)&mono[4 * b];
    }

    __syncthreads();

    v2f As0[T] = {}, As1[T] = {};
    v2f A00[T] = {}, A01[T] = {};
    v2f A10[T] = {}, A11[T] = {};

    const int base = h * NHALF;
#pragma unroll 4
    for (int it = 0; it < NHALF / 256; ++it) {      // 8 iterations
        const int j = base + it * 256 + lane * 4;
        float4 fm0 = *(const float4*)&s_m0[j];
        float4 fm1 = *(const float4*)&s_m1[j];
        float4 fn0 = *(const float4*)&s_n0[j];
        float4 fn1 = *(const float4*)&s_n1[j];
        float4 fi0 = *(const float4*)&s_I0[j];
        float4 fcv = *(const float4*)&s_cv[j];
        v2f Ms0[2] = {{fm0.x, fm0.y}, {fm0.z, fm0.w}};
        v2f Ms1[2] = {{fm1.x, fm1.y}, {fm1.z, fm1.w}};
        v2f Nn0[2] = {{fn0.x, fn0.y}, {fn0.z, fn0.w}};
        v2f Nn1[2] = {{fn1.x, fn1.y}, {fn1.z, fn1.w}};
        v2f Iv[2]  = {{fi0.x, fi0.y}, {fi0.z, fi0.w}};
        v2f Cv[2]  = {{fcv.x, fcv.y}, {fcv.z, fcv.w}};
#pragma unroll
        for (int p = 0; p < 2; ++p) {
#pragma unroll
            for (int t = 0; t < T; ++t) {
                v2f x  = Cv[p] + k0[t] * Ms0[p] + k1[t] * Ms1[p] + vo[t] * Iv[p];
                v2f tx = tanh2(x);
                v2f dphi = 1.0f - tx * tx;
                v2f a0 = dphi * Ms0[p];
                v2f a1 = dphi * Ms1[p];
                As0[t] += tx * Nn0[p];
                As1[t] += tx * Nn1[p];
                A00[t] += a0 * Nn0[p];
                A01[t] += a0 * Nn1[p];
                A10[t] += a1 * Nn0[p];
                A11[t] += a1 * Nn1[p];
            }
        }
    }

    // ---- in-wave reduce, publish partials ----
#pragma unroll
    for (int t = 0; t < T; ++t) {
        float r0 = wave_sum(As0[t].x + As0[t].y);
        float r1 = wave_sum(As1[t].x + As1[t].y);
        float r2 = wave_sum(A00[t].x + A00[t].y);
        float r3 = wave_sum(A01[t].x + A01[t].y);
        float r4 = wave_sum(A10[t].x + A10[t].y);
        float r5 = wave_sum(A11[t].x + A11[t].y);
        if (lane == 0) {
            float* rp = &s_red[((g * 2 + h) * 6) * T + t];
            rp[0 * T] = r0; rp[1 * T] = r1; rp[2 * T] = r2;
            rp[3 * T] = r3; rp[4 * T] = r4; rp[5 * T] = r5;
        }
    }
    __syncthreads();

    // ---- epilogue: lanes 0..3 of each h==0 wave, one trial each ----
    if (h == 0 && lane < T) {
        const int t = lane;
        const int b = b0 + t;
        const float* r0p = &s_red[((g * 2 + 0) * 6) * T + t];
        const float* r1p = &s_red[((g * 2 + 1) * 6) * T + t];
        float s0  = r0p[0 * T] + r1p[0 * T];
        float s1  = r0p[1 * T] + r1p[1 * T];
        float j00 = r0p[2 * T] + r1p[2 * T];
        float j01 = r0p[3 * T] + r1p[3 * T];
        float j10 = r0p[4 * T] + r1p[4 * T];
        float j11 = r0p[5 * T] + r1p[5 * T];

        const float uo  = amp * sinf(e_p);
        const float a00 = alpha[0], a01 = alpha[1], a02 = alpha[2];
        const float a10 = alpha[3], a11 = alpha[4], a12 = alpha[5];
        const float invN = 1.0f / 4096.0f;
        const float DT = 0.0005f;

        float ua0 = uo * a00 + st0 * a01 + st1 * a02;
        float ua1 = uo * a10 + st0 * a11 + st1 * a12;
        float dK0 = 10.0f * (-e_k0 + s0 * invN + ua0);
        float dK1 = 10.0f * (-e_k1 + s1 * invN + ua1);
        out[2 * b]     = fmaf(DT, dK0, e_k0);
        out[2 * b + 1] = fmaf(DT, dK1, e_k1);
        out[B_SIZE * 2 + b] = e_p + DT * w;
        float J00 = 10.0f * (j00 * invN - 1.0f);
        float J01 = 10.0f * (j01 * invN);
        float J10 = 10.0f * (j10 * invN);
        float J11 = 10.0f * (j11 * invN - 1.0f);
        float M00 = e_mono.x, M01 = e_mono.y;
        float M10 = e_mono.z, M11 = e_mono.w;
        float* om = out + B_SIZE * 3 + 4 * b;
        om[0] = M00 + DT * (J00 * M00 + J01 * M10);
        om[1] = M01 + DT * (J00 * M01 + J01 * M11);
        om[2] = M10 + DT * (J10 * M00 + J11 * M10);
        om[3] = M11 + DT * (J10 * M01 + J11 * M11);
        out[B_SIZE * 7 + b] = e_dn + sqrtf(dK0 * dK0 + dK1 * dK1);
    }
}

extern "C" void kernel_launch(void* const* d_in, const int* in_sizes, int n_in,
                              void* d_out, int out_size, void* d_ws, size_t ws_size,
                              hipStream_t stream) {
    const float* k_t   = (const float*)d_in[0];
    const float* phase = (const float*)d_in[1];
    const float* mono  = (const float*)d_in[2];
    const float* dKn   = (const float*)d_in[3];
    const float* amp   = (const float*)d_in[4];
    const float* w     = (const float*)d_in[5];
    const float* stim  = (const float*)d_in[6];
    const float* alpha = (const float*)d_in[7];
    const float* Im    = (const float*)d_in[8];
    const float* mm    = (const float*)d_in[9];
    const float* nm    = (const float*)d_in[10];
    float* out = (float*)d_out;

    // 256 blocks x 1024 threads: 1 block/CU, 16 waves/CU, 32 trials/block
    bif_kernel<<<B_SIZE / 32, 1024, 0, stream>>>(
        k_t, phase, mono, dKn, amp, w, stim, alpha, Im, mm, nm, out);
}

// Round 5
// 25.090 us; speedup vs baseline: 1.1609x; 1.1609x over previous
//
#include <hip/hip_runtime.h>
#include <math.h>

#define N_SIZE 4096
#define B_SIZE 8192
#define T 4                     // trials per wave
#define C2L2E 2.885390081777927f   // 2*log2(e)

typedef float v2f __attribute__((ext_vector_type(2)));

__device__ __forceinline__ float wave_sum(float v) {
#pragma unroll
    for (int off = 32; off >= 1; off >>= 1)
        v += __shfl_xor(v, off, 64);
    return v;
}

// xe = 2*log2e*x (pre-scaled by coefficient folding); tanh = 1 - 2/(2^xe + 1)
// exp2 overflow -> rcp(inf)=0 -> +1; underflow -> d=1 -> 1-2 = -1.  Exact.
__device__ __forceinline__ v2f tanh2_xe(v2f xe) {
    v2f ex;
    ex.x = __builtin_amdgcn_exp2f(xe.x);
    ex.y = __builtin_amdgcn_exp2f(xe.y);
    v2f d = ex + 1.0f;
    v2f r;
    r.x = __builtin_amdgcn_rcpf(d.x);
    r.y = __builtin_amdgcn_rcpf(d.y);
    return 1.0f - 2.0f * r;
}

__global__ __launch_bounds__(512, 2)   // 2 waves/SIMD -> 256 VGPR budget
void bif_kernel(const float* __restrict__ k_t,
                const float* __restrict__ phase,
                const float* __restrict__ mono,
                const float* __restrict__ dKn,
                const float* __restrict__ amp_p,
                const float* __restrict__ w_p,
                const float* __restrict__ stim,
                const float* __restrict__ alpha,
                const float* __restrict__ Im,
                const float* __restrict__ mm,
                const float* __restrict__ nm,
                float* __restrict__ out) {
    __shared__ float s_m0[N_SIZE], s_m1[N_SIZE], s_n0[N_SIZE], s_n1[N_SIZE];
    __shared__ float s_I0[N_SIZE], s_cvc[N_SIZE];   // s_cvc pre-scaled by 2*log2e

    const int tid  = threadIdx.x;
    const int lane = tid & 63;
    const int wid  = tid >> 6;            // 0..7
    const int b0   = blockIdx.x * 32 + wid * T;

    const float st0 = stim[0];
    const float st1 = stim[1];

    // ---- stage 96KB once: 512 threads x 2 float4 per array ----
#pragma unroll
    for (int h = 0; h < 2; ++h) {
        const int t4 = h * 2048 + tid * 4;
        *(float4*)&s_m0[t4] = *(const float4*)&mm[t4];
        *(float4*)&s_m1[t4] = *(const float4*)&mm[N_SIZE + t4];
        *(float4*)&s_n0[t4] = *(const float4*)&nm[t4];
        *(float4*)&s_n1[t4] = *(const float4*)&nm[N_SIZE + t4];
        *(float4*)&s_I0[t4] = *(const float4*)&Im[t4];
        float4 i1 = *(const float4*)&Im[N_SIZE + t4];
        float4 i2 = *(const float4*)&Im[2 * N_SIZE + t4];
        float4 cv;
        cv.x = C2L2E * (st0 * i1.x + st1 * i2.x);
        cv.y = C2L2E * (st0 * i1.y + st1 * i2.y);
        cv.z = C2L2E * (st0 * i1.z + st1 * i2.z);
        cv.w = C2L2E * (st0 * i1.w + st1 * i2.w);
        *(float4*)&s_cvc[t4] = cv;
    }

    // ---- per-trial params ----
    const float amp = amp_p[0];
    const float w   = w_p[0];
    const float tau_sw = w * 0.1f;
    const float phi0 = atanf(tau_sw);
    const float vamp = amp / sqrtf(1.0f + tau_sw * tau_sw);

    float k0r[T], k1r[T];                 // raw (epilogue)
    float k0c[T], k1c[T], voc[T];         // pre-scaled by 2*log2e (loop)
#pragma unroll
    for (int t = 0; t < T; ++t) {
        const int b = b0 + t;
        k0r[t] = k_t[2 * b];
        k1r[t] = k_t[2 * b + 1];
        k0c[t] = C2L2E * k0r[t];
        k1c[t] = C2L2E * k1r[t];
        voc[t] = C2L2E * vamp * sinf(phase[b] - phi0);
    }

    // ---- hoist epilogue globals (latency hidden under main loop) ----
    float  e_p = 0.f, e_dn = 0.f;
    float4 e_mono = {0.f, 0.f, 0.f, 0.f};
    if (lane < T) {
        const int b = b0 + lane;
        e_p  = phase[b];
        e_dn = dKn[b];
        e_mono = *(const float4*)&mono[4 * b];
    }

    __syncthreads();

    v2f As0[T] = {}, As1[T] = {};
    v2f A00[T] = {}, A01[T] = {};
    v2f A10[T] = {}, A11[T] = {};

#pragma unroll 4
    for (int it = 0; it < N_SIZE / 256; ++it) {   // 16 iterations, full N
        const int j = it * 256 + lane * 4;
        float4 fm0 = *(const float4*)&s_m0[j];
        float4 fm1 = *(const float4*)&s_m1[j];
        float4 fn0 = *(const float4*)&s_n0[j];
        float4 fn1 = *(const float4*)&s_n1[j];
        float4 fi0 = *(const float4*)&s_I0[j];
        float4 fcv = *(const float4*)&s_cvc[j];
        v2f Ms0[2] = {{fm0.x, fm0.y}, {fm0.z, fm0.w}};
        v2f Ms1[2] = {{fm1.x, fm1.y}, {fm1.z, fm1.w}};
        v2f Nn0[2] = {{fn0.x, fn0.y}, {fn0.z, fn0.w}};
        v2f Nn1[2] = {{fn1.x, fn1.y}, {fn1.z, fn1.w}};
        v2f Iv[2]  = {{fi0.x, fi0.y}, {fi0.z, fi0.w}};
        v2f Cv[2]  = {{fcv.x, fcv.y}, {fcv.z, fcv.w}};
#pragma unroll
        for (int p = 0; p < 2; ++p) {
#pragma unroll
            for (int t = 0; t < T; ++t) {
                v2f xe = Cv[p] + k0c[t] * Ms0[p] + k1c[t] * Ms1[p] + voc[t] * Iv[p];
                v2f tx = tanh2_xe(xe);
                v2f dphi = 1.0f - tx * tx;
                v2f a0 = dphi * Ms0[p];
                v2f a1 = dphi * Ms1[p];
                As0[t] += tx * Nn0[p];
                As1[t] += tx * Nn1[p];
                A00[t] += a0 * Nn0[p];
                A01[t] += a0 * Nn1[p];
                A10[t] += a1 * Nn0[p];
                A11[t] += a1 * Nn1[p];
            }
        }
    }

    // ---- wave-level reduce; lane t owns trial t ----
    float rs0[T], rs1[T], r00[T], r01[T], r10[T], r11[T];
#pragma unroll
    for (int t = 0; t < T; ++t) {
        rs0[t] = wave_sum(As0[t].x + As0[t].y);
        rs1[t] = wave_sum(As1[t].x + As1[t].y);
        r00[t] = wave_sum(A00[t].x + A00[t].y);
        r01[t] = wave_sum(A01[t].x + A01[t].y);
        r10[t] = wave_sum(A10[t].x + A10[t].y);
        r11[t] = wave_sum(A11[t].x + A11[t].y);
    }

    if (lane < T) {
        const int t = lane;
        const int b = b0 + t;
        // gather this trial's sums (wave_sum broadcast to all lanes; pick via t)
        float s0 = rs0[0], s1 = rs1[0], j00 = r00[0], j01 = r01[0], j10 = r10[0], j11 = r11[0];
#pragma unroll
        for (int q = 1; q < T; ++q) {
            if (t == q) { s0 = rs0[q]; s1 = rs1[q]; j00 = r00[q]; j01 = r01[q]; j10 = r10[q]; j11 = r11[q]; }
        }
        float kk0 = k0r[0], kk1 = k1r[0];
#pragma unroll
        for (int q = 1; q < T; ++q) {
            if (t == q) { kk0 = k0r[q]; kk1 = k1r[q]; }
        }

        const float uo  = amp * sinf(e_p);
        const float a00 = alpha[0], a01 = alpha[1], a02 = alpha[2];
        const float a10 = alpha[3], a11 = alpha[4], a12 = alpha[5];
        const float invN = 1.0f / 4096.0f;
        const float DT = 0.0005f;

        float ua0 = uo * a00 + st0 * a01 + st1 * a02;
        float ua1 = uo * a10 + st0 * a11 + st1 * a12;
        float dK0 = 10.0f * (-kk0 + s0 * invN + ua0);
        float dK1 = 10.0f * (-kk1 + s1 * invN + ua1);
        out[2 * b]     = fmaf(DT, dK0, kk0);
        out[2 * b + 1] = fmaf(DT, dK1, kk1);
        out[B_SIZE * 2 + b] = e_p + DT * w;
        float J00 = 10.0f * (j00 * invN - 1.0f);
        float J01 = 10.0f * (j01 * invN);
        float J10 = 10.0f * (j10 * invN);
        float J11 = 10.0f * (j11 * invN - 1.0f);
        float M00 = e_mono.x, M01 = e_mono.y;
        float M10 = e_mono.z, M11 = e_mono.w;
        float* om = out + B_SIZE * 3 + 4 * b;
        om[0] = M00 + DT * (J00 * M00 + J01 * M10);
        om[1] = M01 + DT * (J00 * M01 + J01 * M11);
        om[2] = M10 + DT * (J10 * M00 + J11 * M10);
        om[3] = M11 + DT * (J10 * M01 + J11 * M11);
        out[B_SIZE * 7 + b] = e_dn + sqrtf(dK0 * dK0 + dK1 * dK1);
    }
}

extern "C" void kernel_launch(void* const* d_in, const int* in_sizes, int n_in,
                              void* d_out, int out_size, void* d_ws, size_t ws_size,
                              hipStream_t stream) {
    const float* k_t   = (const float*)d_in[0];
    const float* phase = (const float*)d_in[1];
    const float* mono  = (const float*)d_in[2];
    const float* dKn   = (const float*)d_in[3];
    const float* amp   = (const float*)d_in[4];
    const float* w     = (const float*)d_in[5];
    const float* stim  = (const float*)d_in[6];
    const float* alpha = (const float*)d_in[7];
    const float* Im    = (const float*)d_in[8];
    const float* mm    = (const float*)d_in[9];
    const float* nm    = (const float*)d_in[10];
    float* out = (float*)d_out;

    // 256 blocks x 512 threads: 1 block/CU (96KB LDS), 8 waves/CU = 2/SIMD,
    // 256 VGPR/wave for deep ILP. 32 trials/block.
    bif_kernel<<<B_SIZE / 32, 512, 0, stream>>>(
        k_t, phase, mono, dKn, amp, w, stim, alpha, Im, mm, nm, out);
}